// Round 2
// baseline (102.409 us; speedup 1.0000x reference)
//
#include <hip/hip_runtime.h>

// CRPS loss: preds [B=8, N=16, C=4, H=128, W=256] f32, gt [8,4,128,256] f32 -> scalar f32
// out = mean_over_points( sum_n |p_n - g|/N  -  sum_{i<j} |p_i - p_j| / (N*(N-1)) )
// Fused single kernel: per-block reduce -> one atomicAdd per block into d_out.

#define CHW      131072            // C*H*W = 4*128*256
#define CHW4     32768             // CHW/4 (float4 units)
#define NENS     16
#define BATCH    8
#define NPOINTS  (BATCH * CHW)     // 1,048,576 spatial points
#define NP4      (NPOINTS / 4)     // 262,144 float4 points
#define BLOCK    256
#define GRID1    (NP4 / BLOCK)     // 1024 blocks

__global__ __launch_bounds__(BLOCK) void crps_fused_kernel(
    const float4* __restrict__ preds,   // [B, N, CHW/4] in float4 units
    const float4* __restrict__ gt,      // [B, CHW/4]
    float* __restrict__ out)            // scalar, pre-zeroed
{
    const int t  = blockIdx.x * BLOCK + threadIdx.x;  // float4 point id over [B, CHW/4]
    const int b  = t >> 15;                            // / CHW4
    const int s4 = t & (CHW4 - 1);

    const float4* pbase = preds + ((b * NENS) << 15) + s4;
    const float4 g = gt[t];

    float4 p[NENS];
#pragma unroll
    for (int n = 0; n < NENS; ++n)
        p[n] = pbase[n << 15];   // stride CHW4 float4 between ensemble members

    float a1 = 0.0f;  // sum |p_i - g|
    float a2 = 0.0f;  // sum_{i<j} |p_i - p_j|
#pragma unroll
    for (int i = 0; i < NENS; ++i) {
        a1 += fabsf(p[i].x - g.x) + fabsf(p[i].y - g.y)
            + fabsf(p[i].z - g.z) + fabsf(p[i].w - g.w);
#pragma unroll
        for (int j = i + 1; j < NENS; ++j) {
            a2 += fabsf(p[i].x - p[j].x) + fabsf(p[i].y - p[j].y)
                + fabsf(p[i].z - p[j].z) + fabsf(p[i].w - p[j].w);
        }
    }
    float local = a1 * (1.0f / 16.0f) - a2 * (1.0f / 240.0f);

    // wave (64-lane) shuffle reduction
#pragma unroll
    for (int off = 32; off > 0; off >>= 1)
        local += __shfl_down(local, off, 64);

    __shared__ float smem[BLOCK / 64];
    const int lane = threadIdx.x & 63;
    const int wid  = threadIdx.x >> 6;
    if (lane == 0) smem[wid] = local;
    __syncthreads();
    if (threadIdx.x == 0) {
        float s = 0.0f;
#pragma unroll
        for (int w = 0; w < BLOCK / 64; ++w) s += smem[w];
        atomicAdd(out, s * (1.0f / (float)NPOINTS));  // device-scope by default on CDNA
    }
}

extern "C" void kernel_launch(void* const* d_in, const int* in_sizes, int n_in,
                              void* d_out, int out_size, void* d_ws, size_t ws_size,
                              hipStream_t stream) {
    const float4* preds = (const float4*)d_in[0];
    const float4* gt    = (const float4*)d_in[1];
    float* out          = (float*)d_out;

    hipMemsetAsync(out, 0, sizeof(float), stream);  // capture-legal stream op
    crps_fused_kernel<<<GRID1, BLOCK, 0, stream>>>(preds, gt, out);
}

// Round 3
// 93.174 us; speedup vs baseline: 1.0991x; 1.0991x over previous
//
#include <hip/hip_runtime.h>

// CRPS loss: preds [B=8, N=16, C=4, H=128, W=256] f32, gt [8,4,128,256] f32 -> scalar f32
// out = mean_over_points( sum_n |p_n - g|/N  -  sum_{i<j} |p_i - p_j| / (N*(N-1)) )
// Two-kernel deterministic reduction (fused atomic version regressed +8us: 1024
// same-address device atomics serialize on the cross-XCD path).
// Per-component accumulators (x/y/z/w) give 4x ILP on the fp-add dep chains.

#define CHW      131072            // C*H*W = 4*128*256
#define CHW4     32768             // CHW/4 (float4 units)
#define NENS     16
#define BATCH    8
#define NPOINTS  (BATCH * CHW)     // 1,048,576 spatial points
#define NP4      (NPOINTS / 4)     // 262,144 float4 points
#define BLOCK    256
#define GRID1    (NP4 / BLOCK)     // 1024 blocks

__global__ __launch_bounds__(BLOCK) void crps_partial_kernel(
    const float4* __restrict__ preds,   // [B, N, CHW/4] in float4 units
    const float4* __restrict__ gt,      // [B, CHW/4]
    float* __restrict__ partial)        // [GRID1]
{
    const int t  = blockIdx.x * BLOCK + threadIdx.x;  // float4 point id over [B, CHW/4]
    const int b  = t >> 15;                            // / CHW4
    const int s4 = t & (CHW4 - 1);

    const float4* pbase = preds + ((b * NENS) << 15) + s4;
    const float4 g = gt[t];

    float4 p[NENS];
#pragma unroll
    for (int n = 0; n < NENS; ++n)
        p[n] = pbase[n << 15];   // stride CHW4 float4 between ensemble members

    // 4 independent accumulator chains per term (x/y/z/w) for ILP
    float a1x = 0.f, a1y = 0.f, a1z = 0.f, a1w = 0.f;
    float a2x = 0.f, a2y = 0.f, a2z = 0.f, a2w = 0.f;
#pragma unroll
    for (int i = 0; i < NENS; ++i) {
        a1x += fabsf(p[i].x - g.x);
        a1y += fabsf(p[i].y - g.y);
        a1z += fabsf(p[i].z - g.z);
        a1w += fabsf(p[i].w - g.w);
#pragma unroll
        for (int j = i + 1; j < NENS; ++j) {
            a2x += fabsf(p[i].x - p[j].x);
            a2y += fabsf(p[i].y - p[j].y);
            a2z += fabsf(p[i].z - p[j].z);
            a2w += fabsf(p[i].w - p[j].w);
        }
    }
    float local = (a1x + a1y + a1z + a1w) * (1.0f / 16.0f)
                - (a2x + a2y + a2z + a2w) * (1.0f / 240.0f);

    // wave (64-lane) shuffle reduction
#pragma unroll
    for (int off = 32; off > 0; off >>= 1)
        local += __shfl_down(local, off, 64);

    __shared__ float smem[BLOCK / 64];
    const int lane = threadIdx.x & 63;
    const int wid  = threadIdx.x >> 6;
    if (lane == 0) smem[wid] = local;
    __syncthreads();
    if (threadIdx.x == 0) {
        float s = 0.0f;
#pragma unroll
        for (int w = 0; w < BLOCK / 64; ++w) s += smem[w];
        partial[blockIdx.x] = s;
    }
}

__global__ __launch_bounds__(BLOCK) void crps_final_kernel(
    const float* __restrict__ partial, float* __restrict__ out)
{
    float local = 0.0f;
    for (int i = threadIdx.x; i < GRID1; i += BLOCK)
        local += partial[i];
#pragma unroll
    for (int off = 32; off > 0; off >>= 1)
        local += __shfl_down(local, off, 64);

    __shared__ float smem[BLOCK / 64];
    const int lane = threadIdx.x & 63;
    const int wid  = threadIdx.x >> 6;
    if (lane == 0) smem[wid] = local;
    __syncthreads();
    if (threadIdx.x == 0) {
        float s = 0.0f;
#pragma unroll
        for (int w = 0; w < BLOCK / 64; ++w) s += smem[w];
        out[0] = s * (1.0f / (float)NPOINTS);
    }
}

extern "C" void kernel_launch(void* const* d_in, const int* in_sizes, int n_in,
                              void* d_out, int out_size, void* d_ws, size_t ws_size,
                              hipStream_t stream) {
    const float4* preds = (const float4*)d_in[0];
    const float4* gt    = (const float4*)d_in[1];
    float* partial      = (float*)d_ws;     // GRID1 floats = 4 KiB scratch
    float* out          = (float*)d_out;

    crps_partial_kernel<<<GRID1, BLOCK, 0, stream>>>(preds, gt, partial);
    crps_final_kernel<<<1, BLOCK, 0, stream>>>(partial, out);
}